// Round 8
// baseline (113.933 us; speedup 1.0000x reference)
//
#include <hip/hip_runtime.h>

// Problem constants
#define DIM 128
#define HID 256
#define K2LE 2.885390081777927f   // 2*log2(e): tanh(x) = 1 - 2/(exp2(K2LE*x)+1)
#define NTILES 16                 // HID / 16
#define RNPAD 120                 // rnbf row stride (bf16): 240B = 15*16B, rows 16B-aligned
#define GXPAD 260                 // g_x row stride (f32)

typedef __attribute__((ext_vector_type(8))) short bf16x8;   // 8 bf16 = 4 VGPRs
typedef __attribute__((ext_vector_type(4))) float f32x4;
typedef __attribute__((ext_vector_type(2))) float f32x2;    // -> v_pk_* f32

__device__ __forceinline__ unsigned short f2bf(float f) {
    union { float f; unsigned u; } x; x.f = f;
    unsigned r = x.u + 0x7fffu + ((x.u >> 16) & 1u);   // RNE
    return (unsigned short)(r >> 16);
}

__device__ __forceinline__ float sigmoid_fast(float x) {
    float t = __builtin_amdgcn_exp2f(-x * 1.4426950408889634f);
    return __builtin_amdgcn_rcpf(1.0f + t);
}

// All-reduce sum across a 16-lane DPP row — VALU pipe only, no LDS.
__device__ __forceinline__ float row16_allreduce(float x) {
    int t;
    t = __builtin_amdgcn_update_dpp(0, __float_as_int(x), 0xB1, 0xf, 0xf, true);
    x += __int_as_float(t);
    t = __builtin_amdgcn_update_dpp(0, __float_as_int(x), 0x4E, 0xf, 0xf, true);
    x += __int_as_float(t);
    t = __builtin_amdgcn_update_dpp(0, __float_as_int(x), 0x124, 0xf, 0xf, true);
    x += __int_as_float(t);
    t = __builtin_amdgcn_update_dpp(0, __float_as_int(x), 0x128, 0xf, 0xf, true);
    x += __int_as_float(t);
    return x;
}

// ---------------------------------------------------------------------------
// Prep (16 blocks x 256):
//   block 0: c2p/w2p[(col&15)*16 + (col>>4)] = K2LE*(pivot@W1+b1)[col], w2[col]
//   all:     W1f = bf16(K2LE*W1) in MFMA B-frag order
//  R18 (confirmed -4.2us): block-0 dot de-serialized — 4 independent
//  accumulators, full unroll -> all 128 loads in flight, ~1 latency batch.
// ---------------------------------------------------------------------------
__global__ void k_prep(const float* __restrict__ pivot,
                       const float* __restrict__ W1,
                       const float* __restrict__ b1,
                       const float* __restrict__ w2,
                       float* __restrict__ c2p,
                       float* __restrict__ w2p,
                       uint4* __restrict__ W1f) {
    const int tid = threadIdx.x;
    if (blockIdx.x == 0) {
        float a0 = 0.f, a1 = 0.f, a2 = 0.f, a3 = 0.f;
#pragma unroll
        for (int d = 0; d < DIM; d += 4) {
            a0 = fmaf(pivot[d    ], W1[(d    ) * HID + tid], a0);
            a1 = fmaf(pivot[d + 1], W1[(d + 1) * HID + tid], a1);
            a2 = fmaf(pivot[d + 2], W1[(d + 2) * HID + tid], a2);
            a3 = fmaf(pivot[d + 3], W1[(d + 3) * HID + tid], a3);
        }
        const float a = b1[tid] + ((a0 + a2) + (a1 + a3));
        const int pidx = (tid & 15) * 16 + (tid >> 4);   // col -> [m][i]
        c2p[pidx] = K2LE * a;
        w2p[pidx] = w2[tid];
    }
    const int e  = blockIdx.x * 256 + tid;
    const int m  = e & 15;
    const int q  = (e >> 4) & 3;
    const int kk = (e >> 6) & 3;
    const int nt = e >> 8;
    const int n  = nt * 16 + m;
    const int k0 = kk * 32 + q * 8;
    unsigned w[4];
#pragma unroll
    for (int p = 0; p < 4; ++p) {
        unsigned lo = f2bf(W1[(k0 + 2 * p    ) * HID + n] * K2LE);
        unsigned hi = f2bf(W1[(k0 + 2 * p + 1) * HID + n] * K2LE);
        w[p] = lo | (hi << 16);
    }
    W1f[e] = make_uint4(w[0], w[1], w[2], w[3]);
}

// ---------------------------------------------------------------------------
// Fused main: 2048 blocks x 256 thr, 16 rays/block.
//  R19: rcp merge 4 -> 2 per iter.  Per-iter issue model (confirmed by R6's
//  1:1 cyc->wall match): ~49 VALU x2cy + 22 trans x~16cy; trans ~90%.
//  exp2 (16) and tail (2) are algorithm-minimal; the two P-blocks' rationals
//  merge:  p = (n0*d1 + n1*d0) / (d0*d1)  -> 2 rcp instead of 4.
//  Overflow: den = prod of 8 A's <= 2^~44 realistic extreme << 2^127.
//  Net -2 trans +3 pk = -26 cyc/wave-iter ~= -1.7us.
//  DO NOT perturb entry region / smem decls: R1/R2 flipped codegen into a
//  32-VGPR spill schedule (WRITE 16->45MB signature).  Guard: VGPR~36-40,
//  LDS 20480, WRITE=16384KB.
// ---------------------------------------------------------------------------
__global__ __launch_bounds__(256, 7) void k_main(
    const float* __restrict__ r,      // [B,128]
    const float* __restrict__ s,      // [B]
    const float* __restrict__ pivot,  // [128]
    const float* __restrict__ c2p,    // [256] permuted K2LE*(pivot@W1+b1)
    const float* __restrict__ w2p,    // [256] permuted w2
    const float* __restrict__ b2,     // [1]
    const int* __restrict__ n_iter_p, // [1]
    const uint4* __restrict__ W1f,    // frag-ordered bf16 K2LE*W1
    float* __restrict__ out)          // [B,128]
{
    __shared__ unsigned short rnbf[16][RNPAD];  // 3.75 KB [ray][k] bf16, padded
    __shared__ float g_x[16][GXPAD];            // 16.25 KB [ray][col] f32, padded

    const int tid   = threadIdx.x;
    const int lane  = tid & 63;
    const int wave  = tid >> 6;        // 0..3: nt-group AND ray-group
    const int m     = lane & 15;
    const int q     = lane >> 4;
    const int ray_l = wave * 4 + q;    // this lane's ray (phases 1,3,4)
    const int ray_g = blockIdx.x * 16 + ray_l;
    const int n_iter = *n_iter_p;

    // ---- Phase 1: load r; bf16 copy to LDS for MFMA; dirs NOT kept live ----
    float4 v0 = *(const float4*)&r[ray_g * DIM + m * 8];
    float4 v1 = *(const float4*)&r[ray_g * DIM + m * 8 + 4];
    const float sv  = s[ray_g];
    const float b2v = b2[0];

    float ss = v0.x*v0.x + v0.y*v0.y + v0.z*v0.z + v0.w*v0.w
             + v1.x*v1.x + v1.y*v1.y + v1.z*v1.z + v1.w*v1.w;
    ss = row16_allreduce(ss);
    const float inv = __builtin_amdgcn_rsqf(ss);
    unsigned p0 = (unsigned)f2bf(v0.x*inv) | ((unsigned)f2bf(v0.y*inv) << 16);
    unsigned p1 = (unsigned)f2bf(v0.z*inv) | ((unsigned)f2bf(v0.w*inv) << 16);
    unsigned p2 = (unsigned)f2bf(v1.x*inv) | ((unsigned)f2bf(v1.y*inv) << 16);
    unsigned p3 = (unsigned)f2bf(v1.z*inv) | ((unsigned)f2bf(v1.w*inv) << 16);
    *(uint4*)&rnbf[ray_l][m * 8] = make_uint4(p0, p1, p2, p3);
    __syncthreads();

    // ---- Phase 2: wave w computes nt = 4w..4w+3 for all 16 rays ----
    bf16x8 afrag[4];
#pragma unroll
    for (int kk = 0; kk < 4; ++kk)
        afrag[kk] = *(const bf16x8*)&rnbf[m][kk * 32 + q * 8];

    const bf16x8* __restrict__ wf = (const bf16x8*)W1f;
    const int fb = q * 16 + m;
#pragma unroll
    for (int t = 0; t < 4; ++t) {
        const int nt = wave * 4 + t;
        f32x4 a = {0.f, 0.f, 0.f, 0.f};
#pragma unroll
        for (int kk = 0; kk < 4; ++kk)
            a = __builtin_amdgcn_mfma_f32_16x16x32_bf16(
                    afrag[kk], wf[nt * 256 + kk * 64 + fb], a, 0, 0, 0);
        // D: row(ray) = q*4+reg, col = nt*16+m  (m89-verified layout)
#pragma unroll
        for (int r4 = 0; r4 < 4; ++r4)
            g_x[q * 4 + r4][nt * 16 + m] = a[r4];
    }
    __syncthreads();

    // ---- Phase 3 setup: lane's 16 cols {i*16+m}, re-paired (i, i+4) within
    //      each 8-col block P so both quad-groups live in .x/.y lanes. ----
    f32x2 ga[2][4], ca[2][4], wa[2][4];
#pragma unroll
    for (int P = 0; P < 2; ++P)
#pragma unroll
        for (int v = 0; v < 4; ++v) {
            const int ilo = P * 8 + v;
            ga[P][v].x = g_x[ray_l][ ilo      * 16 + m];
            ga[P][v].y = g_x[ray_l][(ilo + 4) * 16 + m];
        }
    {
        float4 cv0 = *(const float4*)(c2p + m * 16);
        float4 cv1 = *(const float4*)(c2p + m * 16 + 4);
        float4 cv2 = *(const float4*)(c2p + m * 16 + 8);
        float4 cv3 = *(const float4*)(c2p + m * 16 + 12);
        ca[0][0] = (f32x2){cv0.x, cv1.x}; ca[0][1] = (f32x2){cv0.y, cv1.y};
        ca[0][2] = (f32x2){cv0.z, cv1.z}; ca[0][3] = (f32x2){cv0.w, cv1.w};
        ca[1][0] = (f32x2){cv2.x, cv3.x}; ca[1][1] = (f32x2){cv2.y, cv3.y};
        ca[1][2] = (f32x2){cv2.z, cv3.z}; ca[1][3] = (f32x2){cv2.w, cv3.w};
        float4 wv0 = *(const float4*)(w2p + m * 16);
        float4 wv1 = *(const float4*)(w2p + m * 16 + 4);
        float4 wv2 = *(const float4*)(w2p + m * 16 + 8);
        float4 wv3 = *(const float4*)(w2p + m * 16 + 12);
        wa[0][0] = (f32x2){wv0.x, wv1.x}; wa[0][1] = (f32x2){wv0.y, wv1.y};
        wa[0][2] = (f32x2){wv0.z, wv1.z}; wa[0][3] = (f32x2){wv0.w, wv1.w};
        wa[1][0] = (f32x2){wv2.x, wv3.x}; wa[1][1] = (f32x2){wv2.y, wv3.y};
        wa[1][2] = (f32x2){wv2.z, wv3.z}; wa[1][3] = (f32x2){wv2.w, wv3.w};
    }

    f32x2 Sv = wa[0][0] + wa[0][1] + wa[0][2] + wa[0][3]
             + wa[1][0] + wa[1][1] + wa[1][2] + wa[1][3];
    float S = Sv.x + Sv.y;
    S = row16_allreduce(S);
    const float C0 = K2LE * (S + b2v);

    // ---- Phase 3: march.  Packed combine (R17) + merged rational (R19):
    //      per P-block produce num/den; combine across P with one extra
    //      pk_mul+pk_fma+pk_mul, then only 2 scalar rcp per iter. ----
    float alpha = 0.f;
    for (int it = 0; it < n_iter; ++it) {
        const f32x2 alpha2 = {alpha, alpha};
        f32x2 numA[2], denA[2];
#pragma unroll
        for (int P = 0; P < 2; ++P) {
            f32x2 A0 = alpha2 * ga[P][0] + ca[P][0];          // pk_fma
            f32x2 A1 = alpha2 * ga[P][1] + ca[P][1];
            f32x2 A2 = alpha2 * ga[P][2] + ca[P][2];
            f32x2 A3 = alpha2 * ga[P][3] + ca[P][3];
            A0.x = __builtin_amdgcn_exp2f(A0.x); A0.y = __builtin_amdgcn_exp2f(A0.y);
            A1.x = __builtin_amdgcn_exp2f(A1.x); A1.y = __builtin_amdgcn_exp2f(A1.y);
            A2.x = __builtin_amdgcn_exp2f(A2.x); A2.y = __builtin_amdgcn_exp2f(A2.y);
            A3.x = __builtin_amdgcn_exp2f(A3.x); A3.y = __builtin_amdgcn_exp2f(A3.y);
            const f32x2 one = {1.0f, 1.0f};
            A0 += one; A1 += one; A2 += one; A3 += one;       // pk_add
            f32x2 P01 = A0 * A1;                              // pk_mul
            f32x2 P23 = A2 * A3;
            f32x2 n01 = wa[P][0] * A1 + wa[P][1] * A0;        // pk_mul+pk_fma
            f32x2 n23 = wa[P][2] * A3 + wa[P][3] * A2;
            numA[P] = n01 * P23 + n23 * P01;                  // pk_mul+pk_fma
            denA[P] = P01 * P23;                              // pk_mul
        }
        f32x2 numT = numA[0] * denA[1] + numA[1] * denA[0];   // pk_mul+pk_fma
        f32x2 denT = denA[0] * denA[1];                       // pk_mul
        f32x2 iv;
        iv.x = __builtin_amdgcn_rcpf(denT.x);
        iv.y = __builtin_amdgcn_rcpf(denT.y);
        f32x2 p2v = numT * iv;                                // pk_mul
        float p = p2v.x + p2v.y;
        p = row16_allreduce(p);
        float v = __builtin_amdgcn_rcpf(
            __builtin_amdgcn_exp2f(fmaf(-2.0f * K2LE, p, C0)) + 1.0f);
        alpha += fmaf(-0.1f, v, 0.1f);
    }

    // ---- Phase 4: out = pivot + sigmoid(s)*alpha*(r*inv).  Dirs re-loaded
    //      from r (bit-identical values; r is unmodified and L2/L3-hot) ----
    const float sc = sigmoid_fast(sv) * alpha * inv;
    float4 u0 = *(const float4*)&r[ray_g * DIM + m * 8];
    float4 u1 = *(const float4*)&r[ray_g * DIM + m * 8 + 4];
    float4 pv0 = *(const float4*)(pivot + m * 8);
    float4 pv1 = *(const float4*)(pivot + m * 8 + 4);
    float4 o0, o1;
    o0.x = fmaf(sc, u0.x, pv0.x);
    o0.y = fmaf(sc, u0.y, pv0.y);
    o0.z = fmaf(sc, u0.z, pv0.z);
    o0.w = fmaf(sc, u0.w, pv0.w);
    o1.x = fmaf(sc, u1.x, pv1.x);
    o1.y = fmaf(sc, u1.y, pv1.y);
    o1.z = fmaf(sc, u1.z, pv1.z);
    o1.w = fmaf(sc, u1.w, pv1.w);
    *(float4*)(out + ray_g * DIM + m * 8)     = o0;
    *(float4*)(out + ray_g * DIM + m * 8 + 4) = o1;
}

extern "C" void kernel_launch(void* const* d_in, const int* in_sizes, int n_in,
                              void* d_out, int out_size, void* d_ws, size_t ws_size,
                              hipStream_t stream) {
    const float* r      = (const float*)d_in[0];
    const float* s      = (const float*)d_in[1];
    const float* pivot  = (const float*)d_in[2];
    const float* W1     = (const float*)d_in[3];
    const float* b1     = (const float*)d_in[4];
    const float* w2     = (const float*)d_in[5];
    const float* b2     = (const float*)d_in[6];
    const int*   n_iter = (const int*)d_in[7];
    float* out = (float*)d_out;

    const int B = in_sizes[0] / DIM;  // 32768

    char* ws = (char*)d_ws;
    float* c2p = (float*)(ws);             // 1 KB
    float* w2p = (float*)(ws + 1024);      // 1 KB
    uint4* W1f = (uint4*)(ws + 4096);      // 64 KB

    k_prep<<<16, 256, 0, stream>>>(pivot, W1, b1, w2, c2p, w2p, W1f);
    k_main<<<B / 16, 256, 0, stream>>>(r, s, pivot, c2p, w2p, b2, n_iter,
                                       W1f, out);
}